// Round 1
// baseline (1023.067 us; speedup 1.0000x reference)
//
#include <hip/hip_runtime.h>

typedef _Float16 half8 __attribute__((ext_vector_type(8)));
typedef _Float16 half2v __attribute__((ext_vector_type(2)));
typedef float floatx4 __attribute__((ext_vector_type(4)));

namespace {
constexpr int RES = 256;
constexpr float SCALE_ = 0.17677669529663687f;  // 1/sqrt(32)
}

// ---- prep: transpose+convert weights to fp16 in workspace.
// qkv_wt[col][k] (576 x 192), proj_wt[col][k] (192 x 192). ws needs 294912 B.
__global__ void prep_weights(const float* __restrict__ qkv_w,
                             const float* __restrict__ proj_w,
                             _Float16* __restrict__ qkv_wt,
                             _Float16* __restrict__ proj_wt) {
  const int col = blockIdx.x;
  const int k = threadIdx.x;  // 192
  if (col < 576) {
    qkv_wt[col * 192 + k] = (_Float16)qkv_w[(size_t)k * 576 + col];
  } else {
    const int c = col - 576;
    proj_wt[c * 192 + k] = (_Float16)proj_w[(size_t)k * 192 + c];
  }
}

// One block per 8x8 window; 512 threads (8 waves); ~49.8 KB LDS -> 3 blocks/CU.
// MFMA layouts (16x16x32 f16): A[m=lane&15][k=quad*8+j] (8 contiguous halfs),
// B[k=quad*8+j][n=lane&15] (stored n-major so k is contiguous),
// C/D: col=lane&15, row=quad*4+reg.
__global__ __launch_bounds__(512, 6)
void win_attn_mfma(const float* __restrict__ x,
                   const _Float16* __restrict__ qkv_wt,
                   const float* __restrict__ qkv_b,
                   const _Float16* __restrict__ proj_wt,
                   const float* __restrict__ proj_b,
                   float* __restrict__ out) {
  __shared__ _Float16 xs[64][200];  // tokens x channels (A for QKV), 25.6 KB
  __shared__ _Float16 qB[64][40];   // q [tok][d] pre-scaled; REUSED as O_hd  5 KB
  __shared__ _Float16 kB[64][40];   // k [tok][d]                             5 KB
  __shared__ _Float16 vT[32][72];   // v transposed [d][tok]                  4.6 KB
  __shared__ _Float16 st[64][80];   // scores then P, [q][ktok]; stride 40w   10 KB
  __shared__ float rowred[64];      // 1/rowsum

  // XCD-aware bijective swizzle: consecutive bid round-robin XCDs; give each
  // XCD a contiguous 512-window chunk so neighbor windows share an L2
  // (shared 64B read lines fetched once; partial 32B stores line-merge).
  const int wid = ((int)blockIdx.x & 7) * 512 + ((int)blockIdx.x >> 3);
  const int b = wid >> 10, wh = (wid >> 5) & 31, ww = wid & 31;
  const int wv = threadIdx.x >> 6;   // wave 0..7
  const int lane = threadIdx.x & 63;
  const int ln = lane & 15;
  const int quad = lane >> 4;
  const int mt = wv >> 1, ng = wv & 1;  // QKV/proj wave tiling

  // ---- Gather rolled (-4,-4) window -> xs[tok][ch] fp16.
#pragma unroll
  for (int t = 0; t < 3; ++t) {
    const int f = threadIdx.x + t * 512;
    const int c2 = (f & 31) + 32 * (f >> 9);   // channel pair 0..95
    const int tg = (f >> 5) & 15;              // token group (4 tokens)
    const int r = tg >> 1;
    const int cw = (tg & 1) * 4;
    const int h = (wh * 8 + r + 4) & (RES - 1);
    const int w0 = (ww * 8 + cw + 4) & (RES - 1);
    const size_t base = (((size_t)b * 192 + c2 * 2) * RES + h) * RES + w0;
    const float4 va = *reinterpret_cast<const float4*>(x + base);
    const float4 vb = *reinterpret_cast<const float4*>(x + base + (size_t)RES * RES);
    const int tok = tg * 4;
    half2v p;
    p[0] = (_Float16)va.x; p[1] = (_Float16)vb.x;
    *(half2v*)&xs[tok + 0][c2 * 2] = p;
    p[0] = (_Float16)va.y; p[1] = (_Float16)vb.y;
    *(half2v*)&xs[tok + 1][c2 * 2] = p;
    p[0] = (_Float16)va.z; p[1] = (_Float16)vb.z;
    *(half2v*)&xs[tok + 2][c2 * 2] = p;
    p[0] = (_Float16)va.w; p[1] = (_Float16)vb.w;
    *(half2v*)&xs[tok + 3][c2 * 2] = p;
  }
  __syncthreads();

  // Projection accumulator, persistent across heads: out = sum_hd O_hd @ Wp_hd
  floatx4 acc6[6];
#pragma unroll
  for (int i = 0; i < 6; ++i) acc6[i] = (floatx4){0.f, 0.f, 0.f, 0.f};

  for (int hd = 0; hd < 6; ++hd) {
    // ---- QKV for this head: 64 x 96 = 4 mtiles x 6 ntiles; wave -> mt, 3 nt.
    {
      int colb[3];
#pragma unroll
      for (int i = 0; i < 3; ++i) {
        const int nt = ng * 3 + i;
        colb[i] = (nt >> 1) * 192 + hd * 32 + (nt & 1) * 16;
      }
      floatx4 acc[3];
#pragma unroll
      for (int i = 0; i < 3; ++i) acc[i] = (floatx4){0.f, 0.f, 0.f, 0.f};
      __builtin_amdgcn_s_setprio(1);
#pragma unroll
      for (int k = 0; k < 6; ++k) {
        const half8 af = *(const half8*)&xs[mt * 16 + ln][k * 32 + quad * 8];
#pragma unroll
        for (int i = 0; i < 3; ++i) {
          const half8 bf = *(const half8*)(qkv_wt +
              (size_t)(colb[i] + ln) * 192 + k * 32 + quad * 8);
          acc[i] = __builtin_amdgcn_mfma_f32_16x16x32_f16(af, bf, acc[i], 0, 0, 0);
        }
      }
      __builtin_amdgcn_s_setprio(0);
#pragma unroll
      for (int i = 0; i < 3; ++i) {
        const int nt = ng * 3 + i;
        const int sec = nt >> 1;  // 0=q 1=k 2=v
        const float bias = qkv_b[colb[i] + ln];
        const int tok0 = mt * 16 + quad * 4;
        const int d = (nt & 1) * 16 + ln;
        if (sec == 0) {
#pragma unroll
          for (int j = 0; j < 4; ++j)
            qB[tok0 + j][d] = (_Float16)((acc[i][j] + bias) * SCALE_);
        } else if (sec == 1) {
#pragma unroll
          for (int j = 0; j < 4; ++j)
            kB[tok0 + j][d] = (_Float16)(acc[i][j] + bias);
        } else {
#pragma unroll
          for (int j = 0; j < 4; ++j)
            vT[d][tok0 + j] = (_Float16)(acc[i][j] + bias);
        }
      }
    }
    __syncthreads();

    // ---- Scores: 16 tiles (4x4), K=32 -> 1 MFMA each; 2 tiles per wave.
#pragma unroll
    for (int i = 0; i < 2; ++i) {
      const int t = wv * 2 + i;
      const int smt = t >> 2, snt = t & 3;
      const half8 aq = *(const half8*)&qB[smt * 16 + ln][quad * 8];
      const half8 bk = *(const half8*)&kB[snt * 16 + ln][quad * 8];
      floatx4 acc = {0.f, 0.f, 0.f, 0.f};
      acc = __builtin_amdgcn_mfma_f32_16x16x32_f16(aq, bk, acc, 0, 0, 0);
      const int r0 = smt * 16 + quad * 4;
#pragma unroll
      for (int j = 0; j < 4; ++j)
        st[r0 + j][snt * 16 + ln] = (_Float16)acc[j];
    }
    __syncthreads();

    // ---- Softmax: row = tid>>3, its 8 slices sit in 8 ADJACENT lanes of one
    // wave -> shuffle reduction, no LDS round-trips, no extra barriers.
    {
      const int row = threadIdx.x >> 3;
      const int sl = threadIdx.x & 7;
      const half8 hv = *(const half8*)&st[row][sl * 8];
      float m = -3.0e38f;
#pragma unroll
      for (int j = 0; j < 8; ++j) m = fmaxf(m, (float)hv[j]);
      m = fmaxf(m, __shfl_xor(m, 1));
      m = fmaxf(m, __shfl_xor(m, 2));
      m = fmaxf(m, __shfl_xor(m, 4));
      float s = 0.f;
      half8 ev;
#pragma unroll
      for (int j = 0; j < 8; ++j) {
        const float e = __expf((float)hv[j] - m);
        s += e;
        ev[j] = (_Float16)e;
      }
      *(half8*)&st[row][sl * 8] = ev;
      s += __shfl_xor(s, 1);
      s += __shfl_xor(s, 2);
      s += __shfl_xor(s, 4);
      if (sl == 0) rowred[row] = 1.0f / s;
    }
    __syncthreads();

    // ---- O_hd = P @ V: 8 tiles (4mt x 2nt); 1 tile per wave. O_hd -> qB
    // (qB is dead after scores; reused as the 64x32 per-head O buffer).
    {
      const int pmt = wv >> 1, pnt = wv & 1;
      floatx4 acc = {0.f, 0.f, 0.f, 0.f};
#pragma unroll
      for (int ks = 0; ks < 2; ++ks) {
        const half8 ap = *(const half8*)&st[pmt * 16 + ln][ks * 32 + quad * 8];
        const half8 bv = *(const half8*)&vT[pnt * 16 + ln][ks * 32 + quad * 8];
        acc = __builtin_amdgcn_mfma_f32_16x16x32_f16(ap, bv, acc, 0, 0, 0);
      }
      const int tok0 = pmt * 16 + quad * 4;
      const int d = pnt * 16 + ln;
#pragma unroll
      for (int j = 0; j < 4; ++j)
        qB[tok0 + j][d] = (_Float16)(acc[j] * rowred[tok0 + j]);
    }
    __syncthreads();

    // ---- Proj partial: acc6 += O_hd @ proj_w[hd*32 .. hd*32+32, :]; K=32.
    {
      const half8 af = *(const half8*)&qB[mt * 16 + ln][quad * 8];
      __builtin_amdgcn_s_setprio(1);
#pragma unroll
      for (int i = 0; i < 6; ++i) {
        const int c = (ng * 6 + i) * 16 + ln;
        const half8 bf = *(const half8*)(proj_wt +
            (size_t)c * 192 + hd * 32 + quad * 8);
        acc6[i] = __builtin_amdgcn_mfma_f32_16x16x32_f16(af, bf, acc6[i], 0, 0, 0);
      }
      __builtin_amdgcn_s_setprio(0);
    }
    __syncthreads();  // protect qB/kB/vT before next head's QKV writes
  }

  // ---- Epilogue: bias + scatter store (float4, rolled +4,+4).
  {
#pragma unroll
    for (int i = 0; i < 6; ++i) {
      const int c = (ng * 6 + i) * 16 + ln;
      const float bias = proj_b[c];
      const int tok0 = mt * 16 + quad * 4;           // 4 consecutive tokens
      const int r = tok0 >> 3, cw = tok0 & 7;        // same window row
      const int h = (wh * 8 + r + 4) & (RES - 1);
      const int w0 = (ww * 8 + cw + 4) & (RES - 1);  // float4-aligned
      float4 vv;
      vv.x = acc6[i][0] + bias;
      vv.y = acc6[i][1] + bias;
      vv.z = acc6[i][2] + bias;
      vv.w = acc6[i][3] + bias;
      *reinterpret_cast<float4*>(
          out + (((size_t)b * 192 + c) * RES + h) * RES + w0) = vv;
    }
  }
}

extern "C" void kernel_launch(void* const* d_in, const int* in_sizes, int n_in,
                              void* d_out, int out_size, void* d_ws, size_t ws_size,
                              hipStream_t stream) {
  (void)in_sizes; (void)n_in; (void)out_size; (void)ws_size;
  const float* x      = (const float*)d_in[0];
  const float* qkv_w  = (const float*)d_in[1];
  const float* qkv_b  = (const float*)d_in[2];
  const float* proj_w = (const float*)d_in[3];
  const float* proj_b = (const float*)d_in[4];
  float* out = (float*)d_out;

  _Float16* qkv_wt  = (_Float16*)d_ws;              // 576*192 halfs
  _Float16* proj_wt = qkv_wt + 576 * 192;           // 192*192 halfs

  prep_weights<<<768, 192, 0, stream>>>(qkv_w, proj_w, qkv_wt, proj_wt);
  win_attn_mfma<<<4096, 512, 0, stream>>>(x, qkv_wt, qkv_b, proj_wt, proj_b, out);
}